// Round 4
// baseline (19042.804 us; speedup 1.0000x reference)
//
#include <hip/hip_runtime.h>
#include <hip/hip_bf16.h>

typedef __bf16 bf16x8 __attribute__((ext_vector_type(8)));
typedef float  f32x4  __attribute__((ext_vector_type(4)));

#define LR_C 0.001f

__device__ __forceinline__ float sigf(float x){ return 1.0f/(1.0f + __expf(-x)); }

__device__ __forceinline__ ushort f2bu(float x){
  __hip_bfloat16 h = __float2bfloat16(x);
  return *(ushort*)&h;
}
__device__ __forceinline__ float bu2f(ushort u){
  __hip_bfloat16 h = *(__hip_bfloat16*)&u;
  return __bfloat162float(h);
}

// ---------------- prep kernels (weights only, once per launch) ----------------

__global__ void k_cvt_bf16(__hip_bfloat16* dst, const float* src, int n){
  int i = blockIdx.x*256 + threadIdx.x;
  if (i < n) dst[i] = __float2bfloat16(src[i]);
}

// dst[r][c] (stride cd) = c<cs ? src[r][c] : 0
__global__ void k_cvt_pad(__hip_bfloat16* dst, const float* src, int rows, int cs, int cd){
  int i = blockIdx.x*256 + threadIdx.x;
  if (i >= rows*cd) return;
  int r = i / cd, c = i % cd;
  float v = (c < cs) ? src[r*cs + c] : 0.0f;
  dst[i] = __float2bfloat16(v);
}

// dst[n][j] (n<sc, stride dstride, j>=sr zero-padded) = src[j][n]
__global__ void k_transpose(__hip_bfloat16* dst, const float* src, int sr, int sc, int dstride){
  int i = blockIdx.x*256 + threadIdx.x;
  if (i >= sc*dstride) return;
  int n = i / dstride, j = i % dstride;
  float v = (j < sr) ? src[j*sc + n] : 0.0f;
  dst[i] = __float2bfloat16(v);
}

__global__ void k_zero_bf16(__hip_bfloat16* p, int n){
  int i = blockIdx.x*256 + threadIdx.x;
  if (i < n) p[i] = __float2bfloat16(0.0f);
}

// ---------------- per-wave GEMM: C(32 x 16*NT) = A(32xK, LDS) * B(NxK, global)^T ----
// A: [32][lst] bf16 in LDS (row-major, K-contig). B: [N][ldb] bf16 global.
// Wave w owns n-tiles {w + 8*i : i < ntiles}. acc[i][mt] = 16x16 C frag.

template<int NT, int KST>
__device__ __forceinline__ void wave_gemm(
    const ushort* __restrict__ Al, int lst,
    const ushort* __restrict__ Bg, int ldb,
    int w, int l, int ntiles, f32x4 (&acc)[NT][2])
{
  const int fr = l & 15;
  const int ks = (l >> 4) * 8;
#pragma unroll
  for (int i=0;i<NT;i++){
    acc[i][0] = (f32x4){0.f,0.f,0.f,0.f};
    acc[i][1] = (f32x4){0.f,0.f,0.f,0.f};
  }
#pragma unroll 4
  for (int kk=0; kk<KST; ++kk){
    const int k0 = kk*32;
    bf16x8 a0 = *(const bf16x8*)&Al[(     fr)*lst + k0 + ks];
    bf16x8 a1 = *(const bf16x8*)&Al[(16 + fr)*lst + k0 + ks];
#pragma unroll
    for (int i=0;i<NT;i++){
      if (i < ntiles){
        const ushort* bp = Bg + (size_t)((w + 8*i)*16 + fr)*ldb + k0 + ks;
        bf16x8 b = *(const bf16x8*)bp;
        acc[i][0] = __builtin_amdgcn_mfma_f32_16x16x32_bf16(a0, b, acc[i][0], 0,0,0);
        acc[i][1] = __builtin_amdgcn_mfma_f32_16x16x32_bf16(a1, b, acc[i][1], 0,0,0);
      }
    }
  }
}

// ---------------- persistent PCN kernel: 1 block = 32 batch rows, 60 cycles ----

#define ST1 1032   // A1/E1 LDS stride (1024 + 8 pad)
#define ST2 520    // A2/E2
#define ST0 808    // E0 (800 + 8)
#define ST3 40     // A3

__global__ __launch_bounds__(512, 2)
void pcn_persist(const float* __restrict__ input,
                 const float* __restrict__ s1g, const float* __restrict__ s2g,
                 const float* __restrict__ s3g,
                 const ushort* __restrict__ W1b, const ushort* __restrict__ W2b,
                 const ushort* __restrict__ W3b,
                 const ushort* __restrict__ W1T, const ushort* __restrict__ W2T,
                 const ushort* __restrict__ W3T,
                 float* __restrict__ out)
{
  __shared__ __align__(16) ushort A1E1[32*ST1];  // A1 (sig s1) <-> e1 <-> A1new
  __shared__ __align__(16) ushort A2E2[32*ST2];  // A2 <-> e2 <-> A2new
  __shared__ __align__(16) ushort E0v [32*ST0];  // e0 (cols 784..799 stay 0)
  __shared__ __align__(16) ushort A3s [32*ST3];  // A3 (cols 10..31 stay 0)

  const int slab = blockIdx.x * 32;
  const int t = threadIdx.x;
  const int w = t >> 6, l = t & 63;
  const int fr = l & 15;
  const int r4 = (l >> 4) * 4;

  // ---- init LDS activations ----
  for (int idx = t; idx < 32*1024; idx += 512){
    int r = idx >> 10, c = idx & 1023;
    A1E1[r*ST1 + c] = f2bu(sigf(s1g[(size_t)(slab+r)*1024 + c]));
  }
  for (int idx = t; idx < 32*512; idx += 512){
    int r = idx >> 9, c = idx & 511;
    A2E2[r*ST2 + c] = f2bu(sigf(s2g[(size_t)(slab+r)*512 + c]));
  }
  for (int idx = t; idx < 32*ST3; idx += 512){
    int r = idx / ST3, c = idx % ST3;
    float v = (c < 10) ? sigf(s3g[(size_t)(slab+r)*10 + c]) : 0.0f;
    A3s[idx] = f2bu(v);
  }
  for (int idx = t; idx < 32*24; idx += 512){       // E0 K-pad cols 784..807 = 0
    int r = idx / 24, c = 784 + idx % 24;
    E0v[r*ST0 + c] = 0;
  }

  // ---- init register states (C-fragment layout) ----
  float s1r[64];
#pragma unroll
  for (int i=0;i<8;i++)
#pragma unroll
    for (int mt=0;mt<2;mt++)
#pragma unroll
      for (int j=0;j<4;j++){
        int row = mt*16 + r4 + j, col = (w+8*i)*16 + fr;
        s1r[i*8+mt*4+j] = s1g[(size_t)(slab+row)*1024 + col];
      }
  float s2r[32];
#pragma unroll
  for (int i=0;i<4;i++)
#pragma unroll
    for (int mt=0;mt<2;mt++)
#pragma unroll
      for (int j=0;j<4;j++){
        int row = mt*16 + r4 + j, col = (w+8*i)*16 + fr;
        s2r[i*8+mt*4+j] = s2g[(size_t)(slab+row)*512 + col];
      }
  float s3r[8];
#pragma unroll
  for (int k=0;k<8;k++) s3r[k] = 0.0f;
  if (w == 0 && fr < 10){
#pragma unroll
    for (int mt=0;mt<2;mt++)
#pragma unroll
      for (int j=0;j<4;j++){
        int row = mt*16 + r4 + j;
        s3r[mt*4+j] = s3g[(size_t)(slab+row)*10 + fr];
      }
  }
  __syncthreads();

  // ---- 60 cycles ----
  for (int c = 0; c < 60; ++c){
    const bool last = (c == 59);

    // op1 (P1): p0 = A1 @ W1b^T (N=784,K=1024); e0 = input - p0 -> E0
    {
      f32x4 acc[7][2];
      const int nt1 = (w == 0) ? 7 : 6;   // tiles w+8i <= 48
      wave_gemm<7,32>(A1E1, ST1, W1b, 1024, w, l, nt1, acc);
#pragma unroll
      for (int i=0;i<7;i++) if (i < nt1){
        int col = (w+8*i)*16 + fr;        // <= 783
#pragma unroll
        for (int mt=0;mt<2;mt++)
#pragma unroll
          for (int j=0;j<4;j++){
            int row = mt*16 + r4 + j;
            float p = acc[i][mt][j];
            float e = input[(size_t)(slab+row)*784 + col] - p;
            E0v[row*ST0 + col] = f2bu(e);
            if (last) out[81920 + (size_t)(slab+row)*784 + col] = p;
          }
      }
    }
    __syncthreads();

    // op2 (P2): p1 = A2 @ W2b^T (N=1024,K=512); e1 = s1 - p1 -> A1E1
    {
      f32x4 acc[8][2];
      wave_gemm<8,16>(A2E2, ST2, W2b, 512, w, l, 8, acc);
#pragma unroll
      for (int i=0;i<8;i++){
        int col = (w+8*i)*16 + fr;
#pragma unroll
        for (int mt=0;mt<2;mt++)
#pragma unroll
          for (int j=0;j<4;j++){
            int row = mt*16 + r4 + j;
            float e1 = s1r[i*8+mt*4+j] - acc[i][mt][j];
            A1E1[row*ST1 + col] = f2bu(e1);
          }
      }
    }
    __syncthreads();

    // op3 (P3): p2 = A3 @ W3b^T (N=512,K=32); e2 = s2 - p2 -> A2E2
    {
      f32x4 acc[4][2];
      wave_gemm<4,1>(A3s, ST3, W3b, 32, w, l, 4, acc);
#pragma unroll
      for (int i=0;i<4;i++){
        int col = (w+8*i)*16 + fr;
#pragma unroll
        for (int mt=0;mt<2;mt++)
#pragma unroll
          for (int j=0;j<4;j++){
            int row = mt*16 + r4 + j;
            float e2 = s2r[i*8+mt*4+j] - acc[i][mt][j];
            A2E2[row*ST2 + col] = f2bu(e2);
          }
      }
    }
    __syncthreads();

    // op6 (U3): g = E2 @ W3T^T (N=16,K=512); s3 += LR*sig'(s3)*g  [wave 0 only]
    if (w == 0){
      f32x4 acc[1][2];
      wave_gemm<1,16>(A2E2, ST2, W3T, 512, 0, l, 1, acc);
#pragma unroll
      for (int mt=0;mt<2;mt++)
#pragma unroll
        for (int j=0;j<4;j++){
          int row = mt*16 + r4 + j;
          float g = acc[0][mt][j];
          float s = s3r[mt*4+j];
          float a = sigf(s);
          float sn = s + LR_C*(a*(1.0f-a)*g);
          s3r[mt*4+j] = sn;
          A3s[row*ST3 + fr] = (fr < 10) ? f2bu(sigf(sn)) : (ushort)0;
        }
    }
    __syncthreads();

    // op5 (U2): g = E1 @ W2T^T (N=512,K=1024); s2 += LR*(-e2 + sig'(s2)*g); A2new
    {
      f32x4 acc[4][2];
      wave_gemm<4,32>(A1E1, ST1, W2T, 1024, w, l, 4, acc);
#pragma unroll
      for (int i=0;i<4;i++){
        int col = (w+8*i)*16 + fr;
#pragma unroll
        for (int mt=0;mt<2;mt++)
#pragma unroll
          for (int j=0;j<4;j++){
            int row = mt*16 + r4 + j;
            float g  = acc[i][mt][j];
            float e2 = bu2f(A2E2[row*ST2 + col]);
            float s  = s2r[i*8+mt*4+j];
            float a  = sigf(s);
            float sn = s + LR_C*(-e2 + a*(1.0f-a)*g);
            s2r[i*8+mt*4+j] = sn;
            A2E2[row*ST2 + col] = f2bu(sigf(sn));
          }
      }
    }
    __syncthreads();

    // op4 (U1): g = E0 @ W1T^T (N=1024,K=800); s1 += LR*(-e1 + sig'(s1)*g); A1new
    {
      f32x4 acc[8][2];
      wave_gemm<8,25>(E0v, ST0, W1T, 800, w, l, 8, acc);
#pragma unroll
      for (int i=0;i<8;i++){
        int col = (w+8*i)*16 + fr;
#pragma unroll
        for (int mt=0;mt<2;mt++)
#pragma unroll
          for (int j=0;j<4;j++){
            int row = mt*16 + r4 + j;
            float g  = acc[i][mt][j];
            float e1 = bu2f(A1E1[row*ST1 + col]);
            float s  = s1r[i*8+mt*4+j];
            float a  = sigf(s);
            float sn = s + LR_C*(-e1 + a*(1.0f-a)*g);
            s1r[i*8+mt*4+j] = sn;
            A1E1[row*ST1 + col] = f2bu(sigf(sn));
          }
      }
    }
    __syncthreads();
  }

  // ---- final: s3 -> out[0 : 81920] ----
  if (w == 0 && fr < 10){
#pragma unroll
    for (int mt=0;mt<2;mt++)
#pragma unroll
      for (int j=0;j<4;j++){
        int row = mt*16 + r4 + j;
        out[(size_t)(slab+row)*10 + fr] = s3r[mt*4+j];
      }
  }
}

// ---------------- host orchestration ----------------

extern "C" void kernel_launch(void* const* d_in, const int* in_sizes, int n_in,
                              void* d_out, int out_size, void* d_ws, size_t ws_size,
                              hipStream_t stream) {
  const float* input = (const float*)d_in[0];
  const float* s1    = (const float*)d_in[1];
  const float* s2    = (const float*)d_in[2];
  const float* s3    = (const float*)d_in[3];
  const float* W1    = (const float*)d_in[4];
  const float* W2    = (const float*)d_in[5];
  const float* W3    = (const float*)d_in[6];
  float* out = (float*)d_out;

  char* ws = (char*)d_ws;
  size_t off = 0;
  auto take = [&](size_t bytes)->char*{
    char* p = ws + off;
    off = (off + bytes + 255) & ~(size_t)255;
    return p;
  };

  __hip_bfloat16* W1b = (__hip_bfloat16*)take(784ull*1024*2);   // [784][1024]
  __hip_bfloat16* W2b = (__hip_bfloat16*)take(1024ull*512*2);   // [1024][512]
  __hip_bfloat16* W3b = (__hip_bfloat16*)take(512ull*32*2);     // [512][32]  K-pad
  __hip_bfloat16* W1T = (__hip_bfloat16*)take(1024ull*800*2);   // [1024][800] K-pad
  __hip_bfloat16* W2T = (__hip_bfloat16*)take(512ull*1024*2);   // [512][1024]
  __hip_bfloat16* W3T = (__hip_bfloat16*)take(16ull*512*2);     // [16][512] N-pad

  auto cdiv = [](int a, int b){ return (a + b - 1) / b; };

  k_cvt_bf16 <<<cdiv(784*1024,256),256,0,stream>>>(W1b, W1, 784*1024);
  k_cvt_bf16 <<<cdiv(1024*512,256),256,0,stream>>>(W2b, W2, 1024*512);
  k_cvt_pad  <<<cdiv(512*32,256),256,0,stream>>>(W3b, W3, 512, 10, 32);
  k_transpose<<<cdiv(1024*800,256),256,0,stream>>>(W1T, W1, 784, 1024, 800);
  k_transpose<<<cdiv(512*1024,256),256,0,stream>>>(W2T, W2, 1024, 512, 1024);
  k_zero_bf16<<<cdiv(16*512,256),256,0,stream>>>(W3T, 16*512);
  k_transpose<<<cdiv(10*512,256),256,0,stream>>>(W3T, W3, 512, 10, 512);

  pcn_persist<<<256, 512, 0, stream>>>(
      input, s1, s2, s3,
      (const ushort*)W1b, (const ushort*)W2b, (const ushort*)W3b,
      (const ushort*)W1T, (const ushort*)W2T, (const ushort*)W3T,
      out);
}

// Round 5
// 7235.824 us; speedup vs baseline: 2.6317x; 2.6317x over previous
//
#include <hip/hip_runtime.h>
#include <hip/hip_bf16.h>

typedef __bf16 bf16x8 __attribute__((ext_vector_type(8)));
typedef float  f32x4  __attribute__((ext_vector_type(4)));

#define LR_C 0.001f

__device__ __forceinline__ float sigf(float x){ return 1.0f/(1.0f + __expf(-x)); }
__device__ __forceinline__ ushort f2bu(float x){ __hip_bfloat16 h = __float2bfloat16(x); return *(ushort*)&h; }
__device__ __forceinline__ float bu2f(ushort u){ __hip_bfloat16 h = *(__hip_bfloat16*)&u; return __bfloat162float(h); }

__device__ __forceinline__ void gload_lds16(const void* g, void* l){
  __builtin_amdgcn_global_load_lds(
      (const __attribute__((address_space(1))) void*)g,
      (__attribute__((address_space(3))) void*)l, 16, 0, 0);
}

// ---------------- prep kernels ----------------

__global__ void k_cvt_bf16(__hip_bfloat16* dst, const float* src, int n){
  int i = blockIdx.x*256 + threadIdx.x;
  if (i < n) dst[i] = __float2bfloat16(src[i]);
}

__global__ void k_cvt_pad(__hip_bfloat16* dst, const float* src, int rows, int cs, int cd){
  int i = blockIdx.x*256 + threadIdx.x;
  if (i >= rows*cd) return;
  int r = i / cd, c = i % cd;
  float v = (c < cs) ? src[r*cs + c] : 0.0f;
  dst[i] = __float2bfloat16(v);
}

// dst[n][j] (n<sc, stride dstride, j>=sr zero) = src[j][n]
__global__ void k_transpose(__hip_bfloat16* dst, const float* src, int sr, int sc, int dstride){
  int i = blockIdx.x*256 + threadIdx.x;
  if (i >= sc*dstride) return;
  int n = i / dstride, j = i % dstride;
  float v = (j < sr) ? src[j*sc + n] : 0.0f;
  dst[i] = __float2bfloat16(v);
}

__global__ void k_init_state(float* sf, __hip_bfloat16* A, const float* s, int n){
  int i = blockIdx.x*256 + threadIdx.x;
  if (i >= n) return;
  float v = s[i];
  sf[i] = v;
  A[i] = __float2bfloat16(sigf(v));
}

// s3: 8192x10 -> s3f (stride 10), A3 (stride 32, cols 10..31 = 0)
__global__ void k_init_s3(float* s3f, __hip_bfloat16* A3, const float* s3){
  int i = blockIdx.x*256 + threadIdx.x;
  if (i >= 8192*32) return;
  int b = i >> 5, c = i & 31;
  if (c < 10){
    float v = s3[b*10 + c];
    s3f[b*10 + c] = v;
    A3[i] = __float2bfloat16(sigf(v));
  } else {
    A3[i] = __float2bfloat16(0.0f);
  }
}

__global__ void k_zero_bf16(__hip_bfloat16* p, int n){
  int i = blockIdx.x*256 + threadIdx.x;
  if (i < n) p[i] = __float2bfloat16(0.0f);
}

__global__ void k_copy_f32(float* dst, const float* src, int n){
  int i = blockIdx.x*256 + threadIdx.x;
  if (i < n) dst[i] = src[i];
}

// ---------------- 128x128 / BK=32 / 4-wave NT GEMM core (round-1, proven) ----
// C = A(8192xK) * B(NxK)^T tile at (brow,bcol). Nclamp clamps B row staging.

__device__ __forceinline__ void gemm128(
    const ushort* __restrict__ A, const ushort* __restrict__ B,
    int lda, int ldb, int K, int Nclamp,
    int brow, int bcol, int t, ushort* As, ushort* Bs, f32x4 (&acc)[4][4])
{
  const int w    = t >> 6;
  const int lane = t & 63;
  const int wr   = (w >> 1) * 64;
  const int wc   = (w & 1) * 64;
  const int fr   = lane & 15;
  const int ks   = (lane >> 4) * 8;

#pragma unroll
  for (int m=0;m<4;m++)
#pragma unroll
    for (int n=0;n<4;n++){ acc[m][n][0]=0.f; acc[m][n][1]=0.f; acc[m][n][2]=0.f; acc[m][n][3]=0.f; }

  const int arow = t >> 2;
  const int acol = (t & 3) * 8;
  const ushort* gA  = A + (size_t)(brow + arow) * lda + acol;
  const ushort* gA2 = gA + (size_t)64 * lda;
  int rb  = bcol + arow;      if (rb  > Nclamp-1) rb  = Nclamp-1;
  int rb2 = bcol + 64 + arow; if (rb2 > Nclamp-1) rb2 = Nclamp-1;
  const ushort* gB  = B + (size_t)rb  * ldb + acol;
  const ushort* gB2 = B + (size_t)rb2 * ldb + acol;

  ushort* ldsA  = &As[w * 512];
  ushort* ldsA2 = &As[2048 + w * 512];
  ushort* ldsB  = &Bs[w * 512];
  ushort* ldsB2 = &Bs[2048 + w * 512];

  for (int k0 = 0; k0 < K; k0 += 32){
    gload_lds16(gA  + k0, ldsA);
    gload_lds16(gA2 + k0, ldsA2);
    gload_lds16(gB  + k0, ldsB);
    gload_lds16(gB2 + k0, ldsB2);
    __syncthreads();

    bf16x8 af[4], bfv[4];
#pragma unroll
    for (int m=0;m<4;m++) af[m]  = *(const bf16x8*)&As[(wr + m*16 + fr)*32 + ks];
#pragma unroll
    for (int n=0;n<4;n++) bfv[n] = *(const bf16x8*)&Bs[(wc + n*16 + fr)*32 + ks];
#pragma unroll
    for (int m=0;m<4;m++)
#pragma unroll
      for (int n=0;n<4;n++)
        acc[m][n] = __builtin_amdgcn_mfma_f32_16x16x32_bf16(af[m], bfv[n], acc[m][n], 0, 0, 0);
    __syncthreads();
  }
}

// XCD-aware block map: by%8 == lid%8 so all bx-tiles of a row-band share an XCD
__device__ __forceinline__ void blockmap(int lid, int nbx, int& brow, int& bcol){
  int by = (lid & 7) + 8 * ((lid >> 3) / nbx);
  int bx = (lid >> 3) % nbx;
  brow = by * 128; bcol = bx * 128;
}

// ---------------- fused dispatch kernels ----------------
// D1 = { P1 (448) | U2 (256) | U3 (64) }   (base=0 full; c=0: grid=448; tail: base=448, grid=320)
// D2 = { P2U1 (512) | P3 (256) }

__global__ __launch_bounds__(256, 2)
void fusedD1(int base,
             const ushort* __restrict__ A1, const ushort* __restrict__ W1b,
             const ushort* __restrict__ inb, ushort* __restrict__ e0, float* p0out,
             const ushort* __restrict__ e1b, const ushort* __restrict__ W2T,
             float* __restrict__ s2f, const ushort* __restrict__ e2b,
             ushort* __restrict__ A2,
             const ushort* __restrict__ W3T, float* __restrict__ s3f,
             ushort* __restrict__ A3)
{
  __shared__ __align__(16) ushort As[128*32];
  __shared__ __align__(16) ushort Bs[128*32];
  const int bid = blockIdx.x + base;
  const int t = threadIdx.x;
  const int w = t >> 6, lane = t & 63;
  const int wr = (w >> 1) * 64, wc = (w & 1) * 64;
  const int fr = lane & 15, r4 = (lane >> 4) * 4;
  f32x4 acc[4][4];

  if (bid < 448){                      // P1: e0 = inb - A1@W1b^T
    int brow, bcol; blockmap(bid, 7, brow, bcol);
    gemm128(A1, W1b, 1024, 1024, 1024, 784, brow, bcol, t, As, Bs, acc);
    const int orow0 = brow + wr + r4, ocol0 = bcol + wc + fr;
#pragma unroll
    for (int m=0;m<4;m++)
#pragma unroll
      for (int n=0;n<4;n++){
        int col = ocol0 + n*16;
        if (col >= 784) continue;
#pragma unroll
        for (int j=0;j<4;j++){
          int row = orow0 + m*16 + j;
          float p = acc[m][n][j];
          float e = bu2f(inb[(size_t)row*784 + col]) - p;
          e0[(size_t)row*800 + col] = f2bu(e);
          if (p0out) p0out[(size_t)row*784 + col] = p;
        }
      }
  } else if (bid < 704){               // U2: s2 += LR*(-e2 + sig'(s2)*(e1@W2))
    int brow, bcol; blockmap(bid - 448, 4, brow, bcol);
    gemm128(e1b, W2T, 1024, 1024, 1024, 512, brow, bcol, t, As, Bs, acc);
    const int orow0 = brow + wr + r4, ocol0 = bcol + wc + fr;
#pragma unroll
    for (int m=0;m<4;m++)
#pragma unroll
      for (int n=0;n<4;n++){
        int col = ocol0 + n*16;
#pragma unroll
        for (int j=0;j<4;j++){
          int row = orow0 + m*16 + j;
          size_t ix = (size_t)row*512 + col;
          float s = s2f[ix];
          float a = sigf(s);
          float e2 = bu2f(e2b[ix]);
          float sn = s + LR_C*(-e2 + a*(1.0f-a)*acc[m][n][j]);
          s2f[ix] = sn;
          A2[ix] = f2bu(sigf(sn));
        }
      }
  } else {                             // U3: s3 += LR*sig'(s3)*(e2@W3)
    int brow = (bid - 704) * 128, bcol = 0;
    gemm128(e2b, W3T, 512, 512, 512, 16, brow, bcol, t, As, Bs, acc);
    const int orow0 = brow + wr + r4, ocol0 = wc + fr;
#pragma unroll
    for (int m=0;m<4;m++)
#pragma unroll
      for (int n=0;n<4;n++){
        int col = ocol0 + n*16;
        if (col >= 10) continue;
#pragma unroll
        for (int j=0;j<4;j++){
          int row = orow0 + m*16 + j;
          float s = s3f[(size_t)row*10 + col];
          float a = sigf(s);
          float sn = s + LR_C*(a*(1.0f-a)*acc[m][n][j]);
          s3f[(size_t)row*10 + col] = sn;
          A3[(size_t)row*32 + col] = f2bu(sigf(sn));
        }
      }
  }
}

__global__ __launch_bounds__(256, 2)
void fusedD2(const ushort* __restrict__ A2, const ushort* __restrict__ W2b,
             const ushort* __restrict__ e0, const ushort* __restrict__ W1T,
             float* __restrict__ s1f, ushort* __restrict__ A1,
             ushort* __restrict__ e1b,
             const ushort* __restrict__ A3, const ushort* __restrict__ W3b,
             const float* __restrict__ s2f, ushort* __restrict__ e2b)
{
  __shared__ __align__(16) ushort As[128*32];
  __shared__ __align__(16) ushort Bs[128*32];
  const int bid = blockIdx.x;
  const int t = threadIdx.x;
  const int w = t >> 6, lane = t & 63;
  const int wr = (w >> 1) * 64, wc = (w & 1) * 64;
  const int fr = lane & 15, r4 = (lane >> 4) * 4;

  if (bid < 512){                      // P2U1 merged (dual accumulator)
    int brow, bcol; blockmap(bid, 8, brow, bcol);
    f32x4 aP[4][4], aU[4][4];
    gemm128(A2, W2b, 512, 512, 512, 1024, brow, bcol, t, As, Bs, aP);   // p1
    gemm128(e0, W1T, 800, 800, 800, 1024, brow, bcol, t, As, Bs, aU);   // e0@W1
    const int orow0 = brow + wr + r4, ocol0 = bcol + wc + fr;
#pragma unroll
    for (int m=0;m<4;m++)
#pragma unroll
      for (int n=0;n<4;n++){
        int col = ocol0 + n*16;
#pragma unroll
        for (int j=0;j<4;j++){
          int row = orow0 + m*16 + j;
          size_t ix = (size_t)row*1024 + col;
          float s  = s1f[ix];
          float e1 = s - aP[m][n][j];
          float a  = sigf(s);
          float sn = s + LR_C*(-e1 + a*(1.0f-a)*aU[m][n][j]);
          s1f[ix] = sn;
          A1[ix]  = f2bu(sigf(sn));
          e1b[ix] = f2bu(e1);
        }
      }
  } else {                             // P3: e2 = s2 - A3@W3b^T
    int brow, bcol; blockmap(bid - 512, 4, brow, bcol);
    f32x4 acc[4][4];
    gemm128(A3, W3b, 32, 32, 32, 512, brow, bcol, t, As, Bs, acc);
    const int orow0 = brow + wr + r4, ocol0 = bcol + wc + fr;
#pragma unroll
    for (int m=0;m<4;m++)
#pragma unroll
      for (int n=0;n<4;n++){
        int col = ocol0 + n*16;
#pragma unroll
        for (int j=0;j<4;j++){
          int row = orow0 + m*16 + j;
          size_t ix = (size_t)row*512 + col;
          float e2 = s2f[ix] - acc[m][n][j];
          e2b[ix] = f2bu(e2);
        }
      }
  }
}

// ---------------- host orchestration ----------------

extern "C" void kernel_launch(void* const* d_in, const int* in_sizes, int n_in,
                              void* d_out, int out_size, void* d_ws, size_t ws_size,
                              hipStream_t stream) {
  const float* input = (const float*)d_in[0];
  const float* s1    = (const float*)d_in[1];
  const float* s2    = (const float*)d_in[2];
  const float* s3    = (const float*)d_in[3];
  const float* W1    = (const float*)d_in[4];
  const float* W2    = (const float*)d_in[5];
  const float* W3    = (const float*)d_in[6];
  float* out = (float*)d_out;

  char* ws = (char*)d_ws;
  size_t off = 0;
  auto take = [&](size_t bytes)->char*{
    char* p = ws + off;
    off = (off + bytes + 255) & ~(size_t)255;
    return p;
  };

  float* s1f = (float*)take(8192ull*1024*4);
  float* s2f = (float*)take(8192ull*512*4);
  float* s3f = (float*)take(8192ull*10*4);
  __hip_bfloat16* A1  = (__hip_bfloat16*)take(8192ull*1024*2);
  __hip_bfloat16* A2  = (__hip_bfloat16*)take(8192ull*512*2);
  __hip_bfloat16* A3  = (__hip_bfloat16*)take(8192ull*32*2);
  __hip_bfloat16* e0  = (__hip_bfloat16*)take(8192ull*800*2);
  __hip_bfloat16* e1b = (__hip_bfloat16*)take(8192ull*1024*2);
  __hip_bfloat16* e2b = (__hip_bfloat16*)take(8192ull*512*2);
  __hip_bfloat16* inb = (__hip_bfloat16*)take(8192ull*784*2);
  __hip_bfloat16* W1b = (__hip_bfloat16*)take(784ull*1024*2);
  __hip_bfloat16* W2b = (__hip_bfloat16*)take(1024ull*512*2);
  __hip_bfloat16* W3b = (__hip_bfloat16*)take(512ull*32*2);
  __hip_bfloat16* W1T = (__hip_bfloat16*)take(1024ull*800*2);
  __hip_bfloat16* W2T = (__hip_bfloat16*)take(512ull*1024*2);
  __hip_bfloat16* W3T = (__hip_bfloat16*)take(16ull*512*2);

  auto cdiv = [](int a, int b){ return (a + b - 1) / b; };

  // --- prep (runs every call; d_ws has no persistent state) ---
  k_cvt_bf16 <<<cdiv(8192*784,256),256,0,stream>>>(inb, input, 8192*784);
  k_cvt_bf16 <<<cdiv(784*1024,256),256,0,stream>>>(W1b, W1, 784*1024);
  k_cvt_bf16 <<<cdiv(1024*512,256),256,0,stream>>>(W2b, W2, 1024*512);
  k_cvt_pad  <<<cdiv(512*32,256),256,0,stream>>>(W3b, W3, 512, 10, 32);
  k_transpose<<<cdiv(1024*800,256),256,0,stream>>>(W1T, W1, 784, 1024, 800);
  k_transpose<<<cdiv(512*1024,256),256,0,stream>>>(W2T, W2, 1024, 512, 1024);
  k_zero_bf16<<<cdiv(16*512,256),256,0,stream>>>(W3T, 16*512);
  k_transpose<<<cdiv(10*512,256),256,0,stream>>>(W3T, W3, 512, 10, 512);
  k_init_state<<<cdiv(8192*1024,256),256,0,stream>>>(s1f, A1, s1, 8192*1024);
  k_init_state<<<cdiv(8192*512,256),256,0,stream>>>(s2f, A2, s2, 8192*512);
  k_init_s3  <<<cdiv(8192*32,256),256,0,stream>>>(s3f, A3, s3);
  k_zero_bf16<<<cdiv(8192*800,256),256,0,stream>>>(e0, 8192*800);   // K-pad cols 784..799

  // --- 60 cycles, 2 dispatches each ---
  for (int c = 0; c < 60; ++c){
    float* p0_dst = (c == 59) ? (out + 8192*10) : nullptr;
    if (c == 0){
      fusedD1<<<448, 256, 0, stream>>>(0, (const ushort*)A1, (const ushort*)W1b,
          (const ushort*)inb, (ushort*)e0, p0_dst,
          (const ushort*)e1b, (const ushort*)W2T, s2f, (const ushort*)e2b,
          (ushort*)A2, (const ushort*)W3T, s3f, (ushort*)A3);
    } else {
      fusedD1<<<768, 256, 0, stream>>>(0, (const ushort*)A1, (const ushort*)W1b,
          (const ushort*)inb, (ushort*)e0, p0_dst,
          (const ushort*)e1b, (const ushort*)W2T, s2f, (const ushort*)e2b,
          (ushort*)A2, (const ushort*)W3T, s3f, (ushort*)A3);
    }
    fusedD2<<<768, 256, 0, stream>>>((const ushort*)A2, (const ushort*)W2b,
        (const ushort*)e0, (const ushort*)W1T, s1f, (ushort*)A1, (ushort*)e1b,
        (const ushort*)A3, (const ushort*)W3b, s2f, (ushort*)e2b);
  }
  // trailing U2(59), U3(59)
  fusedD1<<<320, 256, 0, stream>>>(448, (const ushort*)A1, (const ushort*)W1b,
      (const ushort*)inb, (ushort*)e0, nullptr,
      (const ushort*)e1b, (const ushort*)W2T, s2f, (const ushort*)e2b,
      (ushort*)A2, (const ushort*)W3T, s3f, (ushort*)A3);

  k_copy_f32<<<cdiv(8192*10,256),256,0,stream>>>(out, s3f, 8192*10);
}

// Round 6
// 6126.287 us; speedup vs baseline: 3.1084x; 1.1811x over previous
//
#include <hip/hip_runtime.h>
#include <hip/hip_bf16.h>

typedef __bf16 bf16x8 __attribute__((ext_vector_type(8)));
typedef float  f32x4  __attribute__((ext_vector_type(4)));

#define LR_C 0.001f
#define VMCNT(n) asm volatile("s_waitcnt vmcnt(" #n ")" ::: "memory")
#define CFENCE() asm volatile("" ::: "memory")

__device__ __forceinline__ float sigf(float x){ return 1.0f/(1.0f + __expf(-x)); }
__device__ __forceinline__ ushort f2bu(float x){ __hip_bfloat16 h = __float2bfloat16(x); return *(ushort*)&h; }
__device__ __forceinline__ float bu2f(ushort u){ __hip_bfloat16 h = *(__hip_bfloat16*)&u; return __bfloat162float(h); }

__device__ __forceinline__ void gload_lds16(const void* g, void* l){
  __builtin_amdgcn_global_load_lds(
      (const __attribute__((address_space(1))) void*)g,
      (__attribute__((address_space(3))) void*)l, 16, 0, 0);
}

// ---------------- prep kernels ----------------

__global__ void k_cvt_bf16(__hip_bfloat16* dst, const float* src, int n){
  int i = blockIdx.x*256 + threadIdx.x;
  if (i < n) dst[i] = __float2bfloat16(src[i]);
}

__global__ void k_cvt_pad(__hip_bfloat16* dst, const float* src, int rows, int cs, int cd){
  int i = blockIdx.x*256 + threadIdx.x;
  if (i >= rows*cd) return;
  int r = i / cd, c = i % cd;
  float v = (c < cs) ? src[r*cs + c] : 0.0f;
  dst[i] = __float2bfloat16(v);
}

// dst[n][j] (n<sc, stride dstride, j>=sr zero) = src[j][n]
__global__ void k_transpose(__hip_bfloat16* dst, const float* src, int sr, int sc, int dstride){
  int i = blockIdx.x*256 + threadIdx.x;
  if (i >= sc*dstride) return;
  int n = i / dstride, j = i % dstride;
  float v = (j < sr) ? src[j*sc + n] : 0.0f;
  dst[i] = __float2bfloat16(v);
}

__global__ void k_init_state(float* sf, __hip_bfloat16* A, const float* s, int n){
  int i = blockIdx.x*256 + threadIdx.x;
  if (i >= n) return;
  float v = s[i];
  sf[i] = v;
  A[i] = __float2bfloat16(sigf(v));
}

// s3: 8192x10 -> s3f (stride 10), A3 (stride 32, cols 10..31 = 0)
__global__ void k_init_s3(float* s3f, __hip_bfloat16* A3, const float* s3){
  int i = blockIdx.x*256 + threadIdx.x;
  if (i >= 8192*32) return;
  int b = i >> 5, c = i & 31;
  if (c < 10){
    float v = s3[b*10 + c];
    s3f[b*10 + c] = v;
    A3[i] = __float2bfloat16(sigf(v));
  } else {
    A3[i] = __float2bfloat16(0.0f);
  }
}

__global__ void k_zero_bf16(__hip_bfloat16* p, int n){
  int i = blockIdx.x*256 + threadIdx.x;
  if (i < n) p[i] = __float2bfloat16(0.0f);
}

__global__ void k_copy_f32(float* dst, const float* src, int n){
  int i = blockIdx.x*256 + threadIdx.x;
  if (i < n) dst[i] = src[i];
}

// ---------------- 128x128 / BK=32 / 4-wave NT GEMM, 3-deep pipelined ----
// C = A(8192xK) * B(NxK)^T tile at (brow,bcol). Nclamp clamps B row staging.
// LDS: As/Bs are [3][128][32] ushort rotating buffers (48 KB total).
// Staging source col is XOR-swizzled by (ldsrow&3)<<3; ds_read applies the
// same XOR (both-sides rule) -> 8-way bank conflict becomes 4-way.

__device__ __forceinline__ void gemm128(
    const ushort* __restrict__ A, const ushort* __restrict__ B,
    int lda, int ldb, int K, int Nclamp,
    int brow, int bcol, int t, ushort* As, ushort* Bs, f32x4 (&acc)[4][4])
{
  const int w    = t >> 6;
  const int lane = t & 63;
  const int wr   = (w >> 1) * 64;
  const int wc   = (w & 1) * 64;
  const int fr   = lane & 15;
  const int ks   = (lane >> 4) * 8;
  const int rks  = ks ^ ((fr & 3) << 3);    // swizzled read col (ushort units)

#pragma unroll
  for (int m=0;m<4;m++)
#pragma unroll
    for (int n=0;n<4;n++){ acc[m][n][0]=0.f; acc[m][n][1]=0.f; acc[m][n][2]=0.f; acc[m][n][3]=0.f; }

  const int arow = t >> 2;                                  // LDS row 0..63 (+64 for q=1)
  const int acol = ((t & 3) * 8) ^ ((arow & 3) << 3);       // swizzled source col
  const ushort* gA  = A + (size_t)(brow + arow) * lda + acol;
  const ushort* gA2 = gA + (size_t)64 * lda;                // (arow+64)&3 == arow&3
  int rb  = bcol + arow;      if (rb  > Nclamp-1) rb  = Nclamp-1;
  int rb2 = bcol + 64 + arow; if (rb2 > Nclamp-1) rb2 = Nclamp-1;
  const ushort* gB  = B + (size_t)rb  * ldb + acol;
  const ushort* gB2 = B + (size_t)rb2 * ldb + acol;

  auto STAGE = [&](int buf, int k0){
    ushort* Ab = As + buf*4096;
    ushort* Bb = Bs + buf*4096;
    gload_lds16(gA  + k0, Ab + w*512);
    gload_lds16(gA2 + k0, Ab + 2048 + w*512);
    gload_lds16(gB  + k0, Bb + w*512);
    gload_lds16(gB2 + k0, Bb + 2048 + w*512);
  };

  const int nt = K >> 5;
  STAGE(0, 0);
  if (nt > 1) STAGE(1, 32);
  if (nt > 2) STAGE(2, 64);

  int cur = 0;
  for (int tk = 0; tk < nt; ++tk){
    const int rem = nt - 1 - tk;
    if (rem >= 2)      { VMCNT(8); }   // tile tk landed; tk+1, tk+2 in flight
    else if (rem == 1) { VMCNT(4); }
    else               { VMCNT(0); }
    __builtin_amdgcn_s_barrier();
    CFENCE();

    const ushort* Ab = As + cur*4096;
    const ushort* Bb = Bs + cur*4096;
    bf16x8 af[4], bfv[4];
#pragma unroll
    for (int m=0;m<4;m++) af[m]  = *(const bf16x8*)&Ab[(wr + m*16 + fr)*32 + rks];
#pragma unroll
    for (int n=0;n<4;n++) bfv[n] = *(const bf16x8*)&Bb[(wc + n*16 + fr)*32 + rks];
#pragma unroll
    for (int m=0;m<4;m++)
#pragma unroll
      for (int n=0;n<4;n++)
        acc[m][n] = __builtin_amdgcn_mfma_f32_16x16x32_bf16(af[m], bfv[n], acc[m][n], 0, 0, 0);

    CFENCE();
    __builtin_amdgcn_s_barrier();      // all waves done reading buf[cur]
    CFENCE();
    if (tk + 3 < nt) STAGE(cur, (tk+3)*32);
    cur = cur + 1; if (cur == 3) cur = 0;
  }
  CFENCE();
  __builtin_amdgcn_s_barrier();        // LDS safe for next gemm128 call
  CFENCE();
}

// XCD-aware block map: by%8 == lid%8 so all bx-tiles of a row-band share an XCD
__device__ __forceinline__ void blockmap(int lid, int nbx, int& brow, int& bcol){
  int by = (lid & 7) + 8 * ((lid >> 3) / nbx);
  int bx = (lid >> 3) % nbx;
  brow = by * 128; bcol = bx * 128;
}

// ---------------- fused dispatch kernels ----------------
// D1 = { P1 (448) | U2 (256) | U3 (64) }
// D2 = { P2U1 (512) | P3 (256) }

__global__ __launch_bounds__(256, 3)
void fusedD1(int base,
             const ushort* __restrict__ A1, const ushort* __restrict__ W1b,
             const ushort* __restrict__ inb, ushort* __restrict__ e0, float* p0out,
             const ushort* __restrict__ e1b, const ushort* __restrict__ W2T,
             float* __restrict__ s2f, const ushort* __restrict__ e2b,
             ushort* __restrict__ A2,
             const ushort* __restrict__ W3T, float* __restrict__ s3f,
             ushort* __restrict__ A3)
{
  __shared__ __align__(16) ushort As[3*4096];
  __shared__ __align__(16) ushort Bs[3*4096];
  const int bid = blockIdx.x + base;
  const int t = threadIdx.x;
  const int w = t >> 6, lane = t & 63;
  const int wr = (w >> 1) * 64, wc = (w & 1) * 64;
  const int fr = lane & 15, r4 = (lane >> 4) * 4;
  f32x4 acc[4][4];

  if (bid < 448){                      // P1: e0 = inb - A1@W1b^T
    int brow, bcol; blockmap(bid, 7, brow, bcol);
    gemm128(A1, W1b, 1024, 1024, 1024, 784, brow, bcol, t, As, Bs, acc);
    const int orow0 = brow + wr + r4, ocol0 = bcol + wc + fr;
#pragma unroll
    for (int m=0;m<4;m++)
#pragma unroll
      for (int n=0;n<4;n++){
        int col = ocol0 + n*16;
        if (col >= 784) continue;
#pragma unroll
        for (int j=0;j<4;j++){
          int row = orow0 + m*16 + j;
          float p = acc[m][n][j];
          float e = bu2f(inb[(size_t)row*784 + col]) - p;
          e0[(size_t)row*800 + col] = f2bu(e);
          if (p0out) p0out[(size_t)row*784 + col] = p;
        }
      }
  } else if (bid < 704){               // U2: s2 += LR*(-e2 + sig'(s2)*(e1@W2))
    int brow, bcol; blockmap(bid - 448, 4, brow, bcol);
    gemm128(e1b, W2T, 1024, 1024, 1024, 512, brow, bcol, t, As, Bs, acc);
    const int orow0 = brow + wr + r4, ocol0 = bcol + wc + fr;
#pragma unroll
    for (int m=0;m<4;m++)
#pragma unroll
      for (int n=0;n<4;n++){
        int col = ocol0 + n*16;
#pragma unroll
        for (int j=0;j<4;j++){
          int row = orow0 + m*16 + j;
          size_t ix = (size_t)row*512 + col;
          float s = s2f[ix];
          float a = sigf(s);
          float e2 = bu2f(e2b[ix]);
          float sn = s + LR_C*(-e2 + a*(1.0f-a)*acc[m][n][j]);
          s2f[ix] = sn;
          A2[ix] = f2bu(sigf(sn));
        }
      }
  } else {                             // U3: s3 += LR*sig'(s3)*(e2@W3)
    int brow = (bid - 704) * 128, bcol = 0;
    gemm128(e2b, W3T, 512, 512, 512, 16, brow, bcol, t, As, Bs, acc);
    const int orow0 = brow + wr + r4, ocol0 = wc + fr;
#pragma unroll
    for (int m=0;m<4;m++)
#pragma unroll
      for (int n=0;n<4;n++){
        int col = ocol0 + n*16;
        if (col >= 10) continue;
#pragma unroll
        for (int j=0;j<4;j++){
          int row = orow0 + m*16 + j;
          float s = s3f[(size_t)row*10 + col];
          float a = sigf(s);
          float sn = s + LR_C*(a*(1.0f-a)*acc[m][n][j]);
          s3f[(size_t)row*10 + col] = sn;
          A3[(size_t)row*32 + col] = f2bu(sigf(sn));
        }
      }
  }
}

__global__ __launch_bounds__(256, 2)
void fusedD2(const ushort* __restrict__ A2, const ushort* __restrict__ W2b,
             const ushort* __restrict__ e0, const ushort* __restrict__ W1T,
             float* __restrict__ s1f, ushort* __restrict__ A1,
             ushort* __restrict__ e1b,
             const ushort* __restrict__ A3, const ushort* __restrict__ W3b,
             const float* __restrict__ s2f, ushort* __restrict__ e2b)
{
  __shared__ __align__(16) ushort As[3*4096];
  __shared__ __align__(16) ushort Bs[3*4096];
  const int bid = blockIdx.x;
  const int t = threadIdx.x;
  const int w = t >> 6, lane = t & 63;
  const int wr = (w >> 1) * 64, wc = (w & 1) * 64;
  const int fr = lane & 15, r4 = (lane >> 4) * 4;

  if (bid < 512){                      // P2U1 merged (dual accumulator)
    int brow, bcol; blockmap(bid, 8, brow, bcol);
    f32x4 aP[4][4], aU[4][4];
    gemm128(A2, W2b, 512, 512, 512, 1024, brow, bcol, t, As, Bs, aP);   // p1
    gemm128(e0, W1T, 800, 800, 800, 1024, brow, bcol, t, As, Bs, aU);   // e0@W1
    const int orow0 = brow + wr + r4, ocol0 = bcol + wc + fr;
#pragma unroll
    for (int m=0;m<4;m++)
#pragma unroll
      for (int n=0;n<4;n++){
        int col = ocol0 + n*16;
#pragma unroll
        for (int j=0;j<4;j++){
          int row = orow0 + m*16 + j;
          size_t ix = (size_t)row*1024 + col;
          float s  = s1f[ix];
          float e1 = s - aP[m][n][j];
          float a  = sigf(s);
          float sn = s + LR_C*(-e1 + a*(1.0f-a)*aU[m][n][j]);
          s1f[ix] = sn;
          A1[ix]  = f2bu(sigf(sn));
          e1b[ix] = f2bu(e1);
        }
      }
  } else {                             // P3: e2 = s2 - A3@W3b^T
    int brow, bcol; blockmap(bid - 512, 4, brow, bcol);
    f32x4 acc[4][4];
    gemm128(A3, W3b, 32, 32, 32, 512, brow, bcol, t, As, Bs, acc);
    const int orow0 = brow + wr + r4, ocol0 = bcol + wc + fr;
#pragma unroll
    for (int m=0;m<4;m++)
#pragma unroll
      for (int n=0;n<4;n++){
        int col = ocol0 + n*16;
#pragma unroll
        for (int j=0;j<4;j++){
          int row = orow0 + m*16 + j;
          size_t ix = (size_t)row*512 + col;
          float e2 = s2f[ix] - acc[m][n][j];
          e2b[ix] = f2bu(e2);
        }
      }
  }
}

// ---------------- host orchestration ----------------

extern "C" void kernel_launch(void* const* d_in, const int* in_sizes, int n_in,
                              void* d_out, int out_size, void* d_ws, size_t ws_size,
                              hipStream_t stream) {
  const float* input = (const float*)d_in[0];
  const float* s1    = (const float*)d_in[1];
  const float* s2    = (const float*)d_in[2];
  const float* s3    = (const float*)d_in[3];
  const float* W1    = (const float*)d_in[4];
  const float* W2    = (const float*)d_in[5];
  const float* W3    = (const float*)d_in[6];
  float* out = (float*)d_out;

  char* ws = (char*)d_ws;
  size_t off = 0;
  auto take = [&](size_t bytes)->char*{
    char* p = ws + off;
    off = (off + bytes + 255) & ~(size_t)255;
    return p;
  };

  float* s1f = (float*)take(8192ull*1024*4);
  float* s2f = (float*)take(8192ull*512*4);
  float* s3f = (float*)take(8192ull*10*4);
  __hip_bfloat16* A1  = (__hip_bfloat16*)take(8192ull*1024*2);
  __hip_bfloat16* A2  = (__hip_bfloat16*)take(8192ull*512*2);
  __hip_bfloat16* A3  = (__hip_bfloat16*)take(8192ull*32*2);
  __hip_bfloat16* e0  = (__hip_bfloat16*)take(8192ull*800*2);
  __hip_bfloat16* e1b = (__hip_bfloat16*)take(8192ull*1024*2);
  __hip_bfloat16* e2b = (__hip_bfloat16*)take(8192ull*512*2);
  __hip_bfloat16* inb = (__hip_bfloat16*)take(8192ull*784*2);
  __hip_bfloat16* W1b = (__hip_bfloat16*)take(784ull*1024*2);
  __hip_bfloat16* W2b = (__hip_bfloat16*)take(1024ull*512*2);
  __hip_bfloat16* W3b = (__hip_bfloat16*)take(512ull*32*2);
  __hip_bfloat16* W1T = (__hip_bfloat16*)take(1024ull*800*2);
  __hip_bfloat16* W2T = (__hip_bfloat16*)take(512ull*1024*2);
  __hip_bfloat16* W3T = (__hip_bfloat16*)take(16ull*512*2);

  auto cdiv = [](int a, int b){ return (a + b - 1) / b; };

  // --- prep (runs every call; d_ws has no persistent state) ---
  k_cvt_bf16 <<<cdiv(8192*784,256),256,0,stream>>>(inb, input, 8192*784);
  k_cvt_bf16 <<<cdiv(784*1024,256),256,0,stream>>>(W1b, W1, 784*1024);
  k_cvt_bf16 <<<cdiv(1024*512,256),256,0,stream>>>(W2b, W2, 1024*512);
  k_cvt_pad  <<<cdiv(512*32,256),256,0,stream>>>(W3b, W3, 512, 10, 32);
  k_transpose<<<cdiv(1024*800,256),256,0,stream>>>(W1T, W1, 784, 1024, 800);
  k_transpose<<<cdiv(512*1024,256),256,0,stream>>>(W2T, W2, 1024, 512, 1024);
  k_zero_bf16<<<cdiv(16*512,256),256,0,stream>>>(W3T, 16*512);
  k_transpose<<<cdiv(10*512,256),256,0,stream>>>(W3T, W3, 512, 10, 512);
  k_init_state<<<cdiv(8192*1024,256),256,0,stream>>>(s1f, A1, s1, 8192*1024);
  k_init_state<<<cdiv(8192*512,256),256,0,stream>>>(s2f, A2, s2, 8192*512);
  k_init_s3  <<<cdiv(8192*32,256),256,0,stream>>>(s3f, A3, s3);
  k_zero_bf16<<<cdiv(8192*800,256),256,0,stream>>>(e0, 8192*800);   // K-pad cols 784..799

  // --- 60 cycles, 2 dispatches each ---
  for (int c = 0; c < 60; ++c){
    float* p0_dst = (c == 59) ? (out + 8192*10) : nullptr;
    if (c == 0){
      fusedD1<<<448, 256, 0, stream>>>(0, (const ushort*)A1, (const ushort*)W1b,
          (const ushort*)inb, (ushort*)e0, p0_dst,
          (const ushort*)e1b, (const ushort*)W2T, s2f, (const ushort*)e2b,
          (ushort*)A2, (const ushort*)W3T, s3f, (ushort*)A3);
    } else {
      fusedD1<<<768, 256, 0, stream>>>(0, (const ushort*)A1, (const ushort*)W1b,
          (const ushort*)inb, (ushort*)e0, p0_dst,
          (const ushort*)e1b, (const ushort*)W2T, s2f, (const ushort*)e2b,
          (ushort*)A2, (const ushort*)W3T, s3f, (ushort*)A3);
    }
    fusedD2<<<768, 256, 0, stream>>>((const ushort*)A2, (const ushort*)W2b,
        (const ushort*)e0, (const ushort*)W1T, s1f, (ushort*)A1, (ushort*)e1b,
        (const ushort*)A3, (const ushort*)W3b, s2f, (ushort*)e2b);
  }
  // trailing U2(59), U3(59)
  fusedD1<<<320, 256, 0, stream>>>(448, (const ushort*)A1, (const ushort*)W1b,
      (const ushort*)inb, (ushort*)e0, nullptr,
      (const ushort*)e1b, (const ushort*)W2T, s2f, (const ushort*)e2b,
      (ushort*)A2, (const ushort*)W3T, s3f, (ushort*)A3);

  k_copy_f32<<<cdiv(8192*10,256),256,0,stream>>>(out, s3f, 8192*10);
}